// Round 1
// baseline (1743.666 us; speedup 1.0000x reference)
//
#include <hip/hip_runtime.h>
#include <hip/hip_bf16.h>
#include <math.h>

typedef __bf16 bf16;
typedef bf16 bf16x8 __attribute__((ext_vector_type(8)));
typedef bf16 bf16x4 __attribute__((ext_vector_type(4)));
typedef float f32x4 __attribute__((ext_vector_type(4)));

#define NB    131072
#define DIM   512
#define BATCH 256
#define NPG   512
#define NQ    32
#define NH    8
#define HDIM  64
#define LMD   768
#define NL    2
#define ROWS  (BATCH*NQ)   // 8192

__device__ __forceinline__ float gelu_f(float x) {
    return 0.5f * x * (1.0f + erff(x * 0.70710678118654752f));
}

// ---------------- small setup kernels ----------------

__global__ void k_init_meta(int* counts, int* inv) {
    int i = blockIdx.x * blockDim.x + threadIdx.x;
    if (i < BATCH) counts[i] = 0;
    for (int j = i; j < BATCH * NPG; j += gridDim.x * blockDim.x) inv[j] = -1;
}

__global__ void k_count(const int* __restrict__ bidx, int* counts) {
    int i = blockIdx.x * blockDim.x + threadIdx.x;
    if (i < NB) atomicAdd(&counts[bidx[i]], 1);
}

__global__ void k_scan(const int* __restrict__ counts, int* __restrict__ starts) {
    __shared__ int sh[BATCH];
    int t = threadIdx.x;
    sh[t] = counts[t];
    __syncthreads();
    for (int o = 1; o < BATCH; o <<= 1) {
        int v = (t >= o) ? sh[t - o] : 0;
        __syncthreads();
        sh[t] += v;
        __syncthreads();
    }
    starts[t] = sh[t] - counts[t];
}

__global__ void k_posinv(const int* __restrict__ bidx, const int* __restrict__ starts,
                         int* __restrict__ pos, int* __restrict__ inv) {
    int i = blockIdx.x * blockDim.x + threadIdx.x;
    if (i < NB) {
        int b = bidx[i];
        int p = i - starts[b];
        pos[i] = p;
        if (p >= 0 && p < NPG) inv[b * NPG + p] = i;
    }
}

__global__ void k_f32_to_bf16(const float* __restrict__ src, bf16* __restrict__ dst, long n4) {
    long i = blockIdx.x * (long)blockDim.x + threadIdx.x;
    long stride = (long)gridDim.x * blockDim.x;
    for (; i < n4; i += stride) {
        f32x4 v = ((const f32x4*)src)[i];
        bf16x4 o = { (bf16)v.x, (bf16)v.y, (bf16)v.z, (bf16)v.w };
        ((bf16x4*)dst)[i] = o;
    }
}

__global__ void k_init_h(const float* __restrict__ qt, float* __restrict__ hf, bf16* __restrict__ hb) {
    long n = (long)ROWS * DIM;
    for (long i = blockIdx.x * (long)blockDim.x + threadIdx.x; i < n;
         i += (long)gridDim.x * blockDim.x) {
        float v = qt[i & (NQ * DIM - 1)];
        hf[i] = v;
        hb[i] = (bf16)v;
    }
}

// ---------------- generic C = A @ B^T GEMM (bf16 in, f32 acc) ----------------
// A: [M,K] bf16 row-major (lda=K). B: [N,K] bf16 row-major (ldb=K).
// grid: (N/128, M/128), block 256 (4 waves, each 64x64).

#define EPI_BF16      0
#define EPI_BF16_GELU 1
#define EPI_F32       2
#define EPI_KV        3

template<int EPI>
__global__ __launch_bounds__(256)
void k_gemm_bt(const bf16* __restrict__ A, const bf16* __restrict__ B,
               const float* __restrict__ bias, void* __restrict__ C,
               int K, int N,
               bf16* __restrict__ vt, const int* __restrict__ bidx,
               const int* __restrict__ pos)
{
    __shared__ bf16 Al[2][128 * 64];
    __shared__ bf16 Bl[2][128 * 64];
    const int tid = threadIdx.x;
    const int n0 = blockIdx.x * 128;
    const int m0 = blockIdx.y * 128;
    const int w = tid >> 6, l = tid & 63;
    const int wr = (w >> 1) * 64, wc = (w & 1) * 64;
    const int lr = l & 15, lg = l >> 4;

    f32x4 acc[4][4] = {};
    const int nkt = K >> 6;

    auto stage = [&](int buf, int kt) {
#pragma unroll
        for (int p = 0; p < 4; ++p) {
            int o = p * 4096 + tid * 16;   // byte offset within 16KB tile
            int row = o >> 7, kb = o & 127;
            const bf16* ga = A + (size_t)(m0 + row) * K + kt * 64 + (kb >> 1);
            __builtin_amdgcn_global_load_lds(
                (const __attribute__((address_space(1))) void*)ga,
                (__attribute__((address_space(3))) void*)&Al[buf][o >> 1], 16, 0, 0);
            const bf16* gb = B + (size_t)(n0 + row) * K + kt * 64 + (kb >> 1);
            __builtin_amdgcn_global_load_lds(
                (const __attribute__((address_space(1))) void*)gb,
                (__attribute__((address_space(3))) void*)&Bl[buf][o >> 1], 16, 0, 0);
        }
    };

    stage(0, 0);
    for (int kt = 0; kt < nkt; ++kt) {
        int buf = kt & 1;
        __syncthreads();
        if (kt + 1 < nkt) stage(buf ^ 1, kt + 1);
#pragma unroll
        for (int ks = 0; ks < 2; ++ks) {
            bf16x8 av[4], bv[4];
#pragma unroll
            for (int i = 0; i < 4; ++i)
                av[i] = *(const bf16x8*)&Al[buf][(wr + i * 16 + lr) * 64 + ks * 32 + lg * 8];
#pragma unroll
            for (int j = 0; j < 4; ++j)
                bv[j] = *(const bf16x8*)&Bl[buf][(wc + j * 16 + lr) * 64 + ks * 32 + lg * 8];
#pragma unroll
            for (int i = 0; i < 4; ++i)
#pragma unroll
                for (int j = 0; j < 4; ++j)
                    acc[i][j] = __builtin_amdgcn_mfma_f32_16x16x32_bf16(av[i], bv[j], acc[i][j], 0, 0, 0);
        }
    }

#pragma unroll
    for (int i = 0; i < 4; ++i) {
        int r0 = m0 + wr + i * 16 + lg * 4;
#pragma unroll
        for (int j = 0; j < 4; ++j) {
            int c = n0 + wc + j * 16 + lr;
            float bs = bias ? bias[c] : 0.0f;
            if constexpr (EPI == EPI_KV) {
                if (c < 512) {   // K part: row-major [node, 512]
                    bf16* kb = (bf16*)C;
#pragma unroll
                    for (int r = 0; r < 4; ++r)
                        kb[(size_t)(r0 + r) * 512 + c] = (bf16)(acc[i][j][r] + bs);
                } else {         // V part: transposed per-graph [b][ch][slot]
                    int ch = c - 512;
                    int g0 = bidx[r0], p0 = pos[r0];
                    int g3 = bidx[r0 + 3], p3 = pos[r0 + 3];
                    if (g0 == g3 && p3 == p0 + 3 && (p0 & 3) == 0 && p0 >= 0) {
                        bf16x4 v = { (bf16)(acc[i][j][0] + bs), (bf16)(acc[i][j][1] + bs),
                                     (bf16)(acc[i][j][2] + bs), (bf16)(acc[i][j][3] + bs) };
                        *(bf16x4*)&vt[((size_t)g0 * 512 + ch) * 512 + p0] = v;
                    } else {
#pragma unroll
                        for (int r = 0; r < 4; ++r) {
                            int g = bidx[r0 + r], p = pos[r0 + r];
                            if (p >= 0 && p < NPG)
                                vt[((size_t)g * 512 + ch) * 512 + p] = (bf16)(acc[i][j][r] + bs);
                        }
                    }
                }
            } else {
#pragma unroll
                for (int r = 0; r < 4; ++r) {
                    float val = acc[i][j][r] + bs;
                    size_t idx = (size_t)(r0 + r) * N + c;
                    if constexpr (EPI == EPI_F32)       ((float*)C)[idx] = val;
                    else if constexpr (EPI == EPI_BF16) ((bf16*)C)[idx] = (bf16)val;
                    else                                ((bf16*)C)[idx] = (bf16)gelu_f(val);
                }
            }
        }
    }
}

// ---------------- fused attention: one block per (graph, head) ----------------

__global__ __launch_bounds__(256)
void k_attn(const bf16* __restrict__ q, const bf16* __restrict__ kbuf,
            const bf16* __restrict__ vt, const int* __restrict__ inv,
            const int* __restrict__ counts, bf16* __restrict__ ctx)
{
    __shared__ float S[32][512];
    __shared__ bf16 P[32][520];
    const int bh = blockIdx.x;
    const int b = bh >> 3, h = bh & 7;
    const int tid = threadIdx.x;
    const int w = tid >> 6, l = tid & 63;
    const int lr = l & 15, lg = l >> 4;
    const int cnt = counts[b];

    // phase 1: S = scale * Q K^T ; wave w covers node chunk [w*128, w*128+128)
    bf16x8 qa[2][2];
#pragma unroll
    for (int mf = 0; mf < 2; ++mf)
#pragma unroll
        for (int ks = 0; ks < 2; ++ks)
            qa[mf][ks] = *(const bf16x8*)&q[(size_t)(b * NQ + mf * 16 + lr) * DIM + h * HDIM + ks * 32 + lg * 8];

    const int nc0 = w * 128;
#pragma unroll
    for (int nf = 0; nf < 8; ++nf) {
        int node = nc0 + nf * 16 + lr;
        int idx = inv[b * NPG + node];
        const bf16* krow = kbuf + (size_t)(idx < 0 ? 0 : idx) * 512 + h * HDIM;
        bf16x8 kb0 = *(const bf16x8*)&krow[lg * 8];
        bf16x8 kb1 = *(const bf16x8*)&krow[32 + lg * 8];
#pragma unroll
        for (int mf = 0; mf < 2; ++mf) {
            f32x4 a = {0.f, 0.f, 0.f, 0.f};
            a = __builtin_amdgcn_mfma_f32_16x16x32_bf16(qa[mf][0], kb0, a, 0, 0, 0);
            a = __builtin_amdgcn_mfma_f32_16x16x32_bf16(qa[mf][1], kb1, a, 0, 0, 0);
#pragma unroll
            for (int r = 0; r < 4; ++r)
                S[mf * 16 + lg * 4 + r][node] = a[r] * 0.125f;
        }
    }
    __syncthreads();

    // phase 2: masked softmax, wave w owns rows [w*8, w*8+8)
#pragma unroll 1
    for (int qi = w * 8; qi < w * 8 + 8; ++qi) {
        float mx = -3.4e38f;
#pragma unroll
        for (int e = 0; e < 8; ++e) {
            int c = l + 64 * e;
            mx = fmaxf(mx, (c < cnt) ? S[qi][c] : -3.4e38f);
        }
#pragma unroll
        for (int o = 32; o; o >>= 1) mx = fmaxf(mx, __shfl_xor(mx, o));
        float sum = 0.f, ev[8];
#pragma unroll
        for (int e = 0; e < 8; ++e) {
            int c = l + 64 * e;
            float s = (c < cnt) ? expf(S[qi][c] - mx) : 0.0f;
            ev[e] = s; sum += s;
        }
#pragma unroll
        for (int o = 32; o; o >>= 1) sum += __shfl_xor(sum, o);
        float inv_s = sum > 0.f ? 1.0f / sum : 0.0f;
#pragma unroll
        for (int e = 0; e < 8; ++e)
            P[qi][l + 64 * e] = (bf16)(ev[e] * inv_s);
    }
    __syncthreads();

    // phase 3: ctx = P @ V ; wave w owns head-dim cols [w*16, w*16+16)
#pragma unroll
    for (int mf = 0; mf < 2; ++mf) {
        f32x4 a = {0.f, 0.f, 0.f, 0.f};
        for (int kc = 0; kc < 16; ++kc) {
            bf16x8 pa = *(const bf16x8*)&P[mf * 16 + lr][kc * 32 + lg * 8];
            bf16x8 vb = *(const bf16x8*)&vt[((size_t)b * 512 + h * HDIM + w * 16 + lr) * 512 + kc * 32 + lg * 8];
            a = __builtin_amdgcn_mfma_f32_16x16x32_bf16(pa, vb, a, 0, 0, 0);
        }
#pragma unroll
        for (int r = 0; r < 4; ++r)
            ctx[(size_t)(b * NQ + mf * 16 + lg * 4 + r) * DIM + h * HDIM + w * 16 + lr] = (bf16)a[r];
    }
}

// ---------------- layernorm (one wave per row) ----------------
// MODE 0: out = LN(x + resid) -> f32 + bf16.  MODE 1: out = gelu(LN(x)) -> bf16 only.

template<int MODE>
__global__ __launch_bounds__(256)
void k_ln(const float* __restrict__ x, const float* __restrict__ resid,
          const float* __restrict__ g, const float* __restrict__ bt,
          float* __restrict__ of, bf16* __restrict__ ob, int D)
{
    int wid = blockIdx.x * 4 + (threadIdx.x >> 6);
    int l = threadIdx.x & 63;
    const int ne = D >> 6;     // 8 (D=512) or 12 (D=768)
    const float* xr = x + (size_t)wid * D;
    float v[12];
    float s = 0.f;
    for (int e = 0; e < ne; ++e) {
        float t = xr[l + 64 * e];
        if (MODE == 0) t += resid[(size_t)wid * D + l + 64 * e];
        v[e] = t; s += t;
    }
#pragma unroll
    for (int o = 32; o; o >>= 1) s += __shfl_xor(s, o);
    float mu = s / D;
    float s2 = 0.f;
    for (int e = 0; e < ne; ++e) { float d = v[e] - mu; s2 += d * d; }
#pragma unroll
    for (int o = 32; o; o >>= 1) s2 += __shfl_xor(s2, o);
    float rst = rsqrtf(s2 / D + 1e-5f);
    for (int e = 0; e < ne; ++e) {
        int c = l + 64 * e;
        float y = (v[e] - mu) * rst * g[c] + bt[c];
        if (MODE == 1) y = gelu_f(y);
        if (MODE == 0) of[(size_t)wid * D + c] = y;
        ob[(size_t)wid * D + c] = (bf16)y;
    }
}

// ---------------- host launch ----------------

extern "C" void kernel_launch(void* const* d_in, const int* in_sizes, int n_in,
                              void* d_out, int out_size, void* d_ws, size_t ws_size,
                              hipStream_t stream)
{
    const float* node = (const float*)d_in[0];
    const float* qt   = (const float*)d_in[1];
    const float* ipw  = (const float*)d_in[2];
    const float* ipb  = (const float*)d_in[3];
    const float* opw  = (const float*)d_in[4];
    const float* opb  = (const float*)d_in[5];
    const float* f1w  = (const float*)d_in[6];
    const float* f1b  = (const float*)d_in[7];
    const float* f2w  = (const float*)d_in[8];
    const float* f2b  = (const float*)d_in[9];
    const float* ln1g = (const float*)d_in[10];
    const float* ln1b = (const float*)d_in[11];
    const float* ln2g = (const float*)d_in[12];
    const float* ln2b = (const float*)d_in[13];
    const float* ow1  = (const float*)d_in[14];
    const float* ob1  = (const float*)d_in[15];
    const float* olng = (const float*)d_in[16];
    const float* olnb = (const float*)d_in[17];
    const float* ow2  = (const float*)d_in[18];
    const float* ob2  = (const float*)d_in[19];
    const int*   bidx = (const int*)d_in[20];

    char* ws = (char*)d_ws;
    size_t off = 0;
    auto alloc = [&](size_t bytes) {
        void* p = ws + off;
        off += (bytes + 255) & ~(size_t)255;
        return p;
    };

    int*  counts = (int*)alloc(BATCH * 4);
    int*  starts = (int*)alloc(BATCH * 4);
    int*  pos    = (int*)alloc((size_t)NB * 4);
    int*  inv    = (int*)alloc((size_t)BATCH * NPG * 4);
    bf16* nodeb  = (bf16*)alloc((size_t)NB * DIM * 2);
    bf16* kbuf   = (bf16*)alloc((size_t)NB * DIM * 2);
    bf16* vtb    = (bf16*)alloc((size_t)BATCH * DIM * NPG * 2);
    bf16* wip    = (bf16*)alloc((size_t)NL * 1536 * DIM * 2);
    bf16* wop    = (bf16*)alloc((size_t)NL * DIM * DIM * 2);
    bf16* wf1    = (bf16*)alloc((size_t)NL * 2048 * DIM * 2);
    bf16* wf2    = (bf16*)alloc((size_t)NL * DIM * 2048 * 2);
    bf16* wo1    = (bf16*)alloc((size_t)LMD * DIM * 2);
    bf16* wo2    = (bf16*)alloc((size_t)LMD * LMD * 2);
    float* hf    = (float*)alloc((size_t)ROWS * DIM * 4);
    bf16* hb     = (bf16*)alloc((size_t)ROWS * DIM * 2);
    bf16* qb     = (bf16*)alloc((size_t)ROWS * DIM * 2);
    bf16* ctxb   = (bf16*)alloc((size_t)ROWS * DIM * 2);
    float* tmp   = (float*)alloc((size_t)ROWS * LMD * 4);
    bf16* fmid   = (bf16*)alloc((size_t)ROWS * 2048 * 2);
    bf16* omid   = (bf16*)alloc((size_t)ROWS * LMD * 2);
    (void)ws_size; (void)in_sizes; (void)n_in; (void)out_size;

    k_init_meta<<<512, 256, 0, stream>>>(counts, inv);
    k_count<<<NB / 256, 256, 0, stream>>>(bidx, counts);
    k_scan<<<1, BATCH, 0, stream>>>(counts, starts);
    k_posinv<<<NB / 256, 256, 0, stream>>>(bidx, starts, pos, inv);
    k_f32_to_bf16<<<2048, 256, 0, stream>>>(node, nodeb, (long)NB * DIM / 4);
    k_f32_to_bf16<<<256, 256, 0, stream>>>(ipw, wip, (long)NL * 1536 * DIM / 4);
    k_f32_to_bf16<<<256, 256, 0, stream>>>(opw, wop, (long)NL * DIM * DIM / 4);
    k_f32_to_bf16<<<256, 256, 0, stream>>>(f1w, wf1, (long)NL * 2048 * DIM / 4);
    k_f32_to_bf16<<<256, 256, 0, stream>>>(f2w, wf2, (long)NL * DIM * 2048 / 4);
    k_f32_to_bf16<<<256, 256, 0, stream>>>(ow1, wo1, (long)LMD * DIM / 4);
    k_f32_to_bf16<<<256, 256, 0, stream>>>(ow2, wo2, (long)LMD * LMD / 4);
    k_init_h<<<2048, 256, 0, stream>>>(qt, hf, hb);

    for (int lyr = 0; lyr < NL; ++lyr) {
        const bf16* wq  = wip + (size_t)lyr * 1536 * DIM;
        const bf16* wkv = wq + (size_t)512 * DIM;
        const float* bq  = ipb + lyr * 1536;
        const float* bkv = bq + 512;

        dim3 gkv(1024 / 128, NB / 128);
        k_gemm_bt<EPI_KV><<<gkv, 256, 0, stream>>>(nodeb, wkv, bkv, kbuf, DIM, 1024, vtb, bidx, pos);

        dim3 gq(DIM / 128, ROWS / 128);
        k_gemm_bt<EPI_BF16><<<gq, 256, 0, stream>>>(hb, wq, bq, qb, DIM, DIM, nullptr, nullptr, nullptr);

        k_attn<<<BATCH * NH, 256, 0, stream>>>(qb, kbuf, vtb, inv, counts, ctxb);

        k_gemm_bt<EPI_F32><<<gq, 256, 0, stream>>>(ctxb, wop + (size_t)lyr * DIM * DIM,
                                                   opb + lyr * DIM, tmp, DIM, DIM,
                                                   nullptr, nullptr, nullptr);
        k_ln<0><<<ROWS / 4, 256, 0, stream>>>(tmp, hf, ln1g + lyr * DIM, ln1b + lyr * DIM, hf, hb, DIM);

        dim3 gf1(2048 / 128, ROWS / 128);
        k_gemm_bt<EPI_BF16_GELU><<<gf1, 256, 0, stream>>>(hb, wf1 + (size_t)lyr * 2048 * DIM,
                                                          f1b + lyr * 2048, fmid, DIM, 2048,
                                                          nullptr, nullptr, nullptr);
        k_gemm_bt<EPI_F32><<<gq, 256, 0, stream>>>(fmid, wf2 + (size_t)lyr * DIM * 2048,
                                                   f2b + lyr * DIM, tmp, 2048, DIM,
                                                   nullptr, nullptr, nullptr);
        k_ln<0><<<ROWS / 4, 256, 0, stream>>>(tmp, hf, ln2g + lyr * DIM, ln2b + lyr * DIM, hf, hb, DIM);
    }

    dim3 go1(LMD / 128, ROWS / 128);
    k_gemm_bt<EPI_F32><<<go1, 256, 0, stream>>>(hb, wo1, ob1, tmp, DIM, LMD, nullptr, nullptr, nullptr);
    k_ln<1><<<ROWS / 4, 256, 0, stream>>>(tmp, nullptr, olng, olnb, nullptr, omid, LMD);
    k_gemm_bt<EPI_F32><<<go1, 256, 0, stream>>>(omid, wo2, ob2, (float*)d_out, LMD, LMD, nullptr, nullptr, nullptr);
}

// Round 2
// 1513.286 us; speedup vs baseline: 1.1522x; 1.1522x over previous
//
#include <hip/hip_runtime.h>
#include <hip/hip_bf16.h>
#include <math.h>

typedef __bf16 bf16;
typedef bf16 bf16x8 __attribute__((ext_vector_type(8)));
typedef bf16 bf16x4 __attribute__((ext_vector_type(4)));
typedef float f32x4 __attribute__((ext_vector_type(4)));

#define NB    131072
#define DIM   512
#define BATCH 256
#define NPG   512
#define NQ    32
#define NH    8
#define HDIM  64
#define LMD   768
#define NL    2
#define ROWS  (BATCH*NQ)   // 8192

__device__ __forceinline__ float gelu_f(float x) {
    return 0.5f * x * (1.0f + erff(x * 0.70710678118654752f));
}

// ---------------- small setup kernels ----------------

__global__ void k_init_meta(int* counts, int* inv) {
    int i = blockIdx.x * blockDim.x + threadIdx.x;
    if (i < BATCH) counts[i] = 0;
    for (int j = i; j < BATCH * NPG; j += gridDim.x * blockDim.x) inv[j] = -1;
}

__global__ void k_count(const int* __restrict__ bidx, int* counts) {
    int i = blockIdx.x * blockDim.x + threadIdx.x;
    if (i < NB) atomicAdd(&counts[bidx[i]], 1);
}

__global__ void k_scan(const int* __restrict__ counts, int* __restrict__ starts) {
    __shared__ int sh[BATCH];
    int t = threadIdx.x;
    sh[t] = counts[t];
    __syncthreads();
    for (int o = 1; o < BATCH; o <<= 1) {
        int v = (t >= o) ? sh[t - o] : 0;
        __syncthreads();
        sh[t] += v;
        __syncthreads();
    }
    starts[t] = sh[t] - counts[t];
}

__global__ void k_posinv(const int* __restrict__ bidx, const int* __restrict__ starts,
                         int* __restrict__ pos, int* __restrict__ inv) {
    int i = blockIdx.x * blockDim.x + threadIdx.x;
    if (i < NB) {
        int b = bidx[i];
        int p = i - starts[b];
        pos[i] = p;
        if (p >= 0 && p < NPG) inv[b * NPG + p] = i;
    }
}

__global__ void k_f32_to_bf16(const float* __restrict__ src, bf16* __restrict__ dst, long n4) {
    long i = blockIdx.x * (long)blockDim.x + threadIdx.x;
    long stride = (long)gridDim.x * blockDim.x;
    for (; i < n4; i += stride) {
        f32x4 v = ((const f32x4*)src)[i];
        bf16x4 o = { (bf16)v.x, (bf16)v.y, (bf16)v.z, (bf16)v.w };
        ((bf16x4*)dst)[i] = o;
    }
}

__global__ void k_init_h(const float* __restrict__ qt, float* __restrict__ hf, bf16* __restrict__ hb) {
    long n = (long)ROWS * DIM;
    for (long i = blockIdx.x * (long)blockDim.x + threadIdx.x; i < n;
         i += (long)gridDim.x * blockDim.x) {
        float v = qt[i & (NQ * DIM - 1)];
        hf[i] = v;
        hb[i] = (bf16)v;
    }
}

// ---------------- generic C = A @ B^T GEMM (bf16 in, f32 acc) ----------------
// A: [M,K] bf16 row-major (lda=K). B: [N,K] bf16 row-major (ldb=K).
// grid: (N/128, M/128), block 256 (4 waves, each 64x64).
// XCD-chunked block swizzle (T1): requires gridDim.x*gridDim.y % 8 == 0.

#define EPI_BF16      0
#define EPI_BF16_GELU 1
#define EPI_F32       2
#define EPI_KV        3

template<int EPI>
__global__ __launch_bounds__(256)
void k_gemm_bt(const bf16* __restrict__ A, const bf16* __restrict__ B,
               const float* __restrict__ bias, void* __restrict__ C,
               int K, int N,
               bf16* __restrict__ vt, const int* __restrict__ bidx,
               const int* __restrict__ pos)
{
    // Sm[0..1] = A double-buffer tiles, Sm[2..3] = B double-buffer tiles.
    // Reused after the K-loop as the epilogue repack buffer.
    __shared__ bf16 Sm[4][128 * 64];
    const int tid = threadIdx.x;

    // T1 XCD swizzle: consecutive swizzled ids within one XCD chunk share the
    // same M-panel (N-tile fastest) -> A-panel served from that XCD's L2.
    int nwg = gridDim.x * gridDim.y;
    int lin = blockIdx.y * gridDim.x + blockIdx.x;
    int cpx = nwg >> 3;
    int swz = (lin & 7) * cpx + (lin >> 3);
    const int n0 = (swz % gridDim.x) * 128;
    const int m0 = (swz / gridDim.x) * 128;

    const int w = tid >> 6, l = tid & 63;
    const int wr = (w >> 1) * 64, wc = (w & 1) * 64;
    const int lr = l & 15, lg = l >> 4;

    f32x4 acc[4][4] = {};
    const int nkt = K >> 6;

    auto stage = [&](int buf, int kt) {
#pragma unroll
        for (int p = 0; p < 4; ++p) {
            int o = p * 4096 + tid * 16;   // byte offset within 16KB tile
            int row = o >> 7, kb = o & 127;
            const bf16* ga = A + (size_t)(m0 + row) * K + kt * 64 + (kb >> 1);
            __builtin_amdgcn_global_load_lds(
                (const __attribute__((address_space(1))) void*)ga,
                (__attribute__((address_space(3))) void*)&Sm[buf][o >> 1], 16, 0, 0);
            const bf16* gb = B + (size_t)(n0 + row) * K + kt * 64 + (kb >> 1);
            __builtin_amdgcn_global_load_lds(
                (const __attribute__((address_space(1))) void*)gb,
                (__attribute__((address_space(3))) void*)&Sm[2 + buf][o >> 1], 16, 0, 0);
        }
    };

    stage(0, 0);
    for (int kt = 0; kt < nkt; ++kt) {
        int buf = kt & 1;
        __syncthreads();
        if (kt + 1 < nkt) stage(buf ^ 1, kt + 1);
#pragma unroll
        for (int ks = 0; ks < 2; ++ks) {
            bf16x8 av[4], bv[4];
#pragma unroll
            for (int i = 0; i < 4; ++i)
                av[i] = *(const bf16x8*)&Sm[buf][(wr + i * 16 + lr) * 64 + ks * 32 + lg * 8];
#pragma unroll
            for (int j = 0; j < 4; ++j)
                bv[j] = *(const bf16x8*)&Sm[2 + buf][(wc + j * 16 + lr) * 64 + ks * 32 + lg * 8];
#pragma unroll
            for (int i = 0; i < 4; ++i)
#pragma unroll
                for (int j = 0; j < 4; ++j)
                    acc[i][j] = __builtin_amdgcn_mfma_f32_16x16x32_bf16(av[i], bv[j], acc[i][j], 0, 0, 0);
        }
    }

    // ---- epilogue ----
    if constexpr (EPI == EPI_F32) {
        float* out = (float*)C;
#pragma unroll
        for (int i = 0; i < 4; ++i) {
            int r0 = m0 + wr + i * 16 + lg * 4;
#pragma unroll
            for (int j = 0; j < 4; ++j) {
                int c = n0 + wc + j * 16 + lr;
                float bs = bias ? bias[c] : 0.0f;
#pragma unroll
                for (int r = 0; r < 4; ++r)
                    out[(size_t)(r0 + r) * N + c] = acc[i][j][r] + bs;
            }
        }
    } else {
        // Repack through LDS so global stores are 128B-contiguous rows.
        __syncthreads();   // all waves done ds_reading Sm
        const int SROW = 68;              // pad: 68%4==0 keeps 8B alignment
        bf16* shw = &Sm[0][0] + w * (64 * SROW);
        const bool vblk = (EPI == EPI_KV) && (n0 >= 512);
#pragma unroll
        for (int i = 0; i < 4; ++i) {
#pragma unroll
            for (int j = 0; j < 4; ++j) {
                int c = n0 + wc + j * 16 + lr;
                float bs = bias ? bias[c] : 0.0f;
#pragma unroll
                for (int r = 0; r < 4; ++r) {
                    float val = acc[i][j][r] + bs;
                    if constexpr (EPI == EPI_BF16_GELU) val = gelu_f(val);
                    int rm = i * 16 + lg * 4 + r;   // local m 0..63
                    int cn = j * 16 + lr;           // local n 0..63
                    if (vblk) shw[cn * SROW + rm] = (bf16)val;   // [ch][node]
                    else      shw[rm * SROW + cn] = (bf16)val;   // [m][n]
                }
            }
        }
        if (!vblk) {
            bf16* outp = (bf16*)C;
            size_t ld = (EPI == EPI_KV) ? 512 : (size_t)N;
#pragma unroll
            for (int it = 0; it < 16; ++it) {
                int rm = it * 4 + lg;
                bf16x4 v = *(const bf16x4*)&shw[rm * SROW + lr * 4];
                *(bf16x4*)&outp[(size_t)(m0 + wr + rm) * ld + (n0 + wc + lr * 4)] = v;
            }
        } else {
            int nbase = m0 + wr;
            int ch0 = (n0 - 512) + wc;
            int g0 = bidx[nbase], p0 = pos[nbase];
            bool fast = (bidx[nbase + 63] == g0) && (pos[nbase + 63] == p0 + 63) &&
                        ((p0 & 3) == 0) && (p0 >= 0) && (p0 + 63 < NPG);
            if (fast) {
#pragma unroll
                for (int it = 0; it < 16; ++it) {
                    int ch = it * 4 + lg;
                    bf16x4 v = *(const bf16x4*)&shw[ch * SROW + lr * 4];
                    *(bf16x4*)&vt[((size_t)g0 * 512 + ch0 + ch) * 512 + (p0 + lr * 4)] = v;
                }
            } else {
                for (int it = 0; it < 16; ++it) {
                    int ch = it * 4 + lg;
#pragma unroll
                    for (int e = 0; e < 4; ++e) {
                        int node = nbase + lr * 4 + e;
                        int g = bidx[node], p = pos[node];
                        if (p >= 0 && p < NPG)
                            vt[((size_t)g * 512 + ch0 + ch) * 512 + p] = shw[ch * SROW + lr * 4 + e];
                    }
                }
            }
        }
    }
}

// ---------------- fused attention: one block per (graph, head) ----------------

__global__ __launch_bounds__(256)
void k_attn(const bf16* __restrict__ q, const bf16* __restrict__ kbuf,
            const bf16* __restrict__ vt, const int* __restrict__ inv,
            const int* __restrict__ counts, bf16* __restrict__ ctx)
{
    __shared__ float S[32][512];
    __shared__ bf16 P[32][520];
    const int bh = blockIdx.x;
    const int b = bh >> 3, h = bh & 7;
    const int tid = threadIdx.x;
    const int w = tid >> 6, l = tid & 63;
    const int lr = l & 15, lg = l >> 4;
    const int cnt = counts[b];

    // phase 1: S = scale * Q K^T ; wave w covers node chunk [w*128, w*128+128)
    bf16x8 qa[2][2];
#pragma unroll
    for (int mf = 0; mf < 2; ++mf)
#pragma unroll
        for (int ks = 0; ks < 2; ++ks)
            qa[mf][ks] = *(const bf16x8*)&q[(size_t)(b * NQ + mf * 16 + lr) * DIM + h * HDIM + ks * 32 + lg * 8];

    const int nc0 = w * 128;
#pragma unroll
    for (int nf = 0; nf < 8; ++nf) {
        int node = nc0 + nf * 16 + lr;
        int idx = inv[b * NPG + node];
        const bf16* krow = kbuf + (size_t)(idx < 0 ? 0 : idx) * 512 + h * HDIM;
        bf16x8 kb0 = *(const bf16x8*)&krow[lg * 8];
        bf16x8 kb1 = *(const bf16x8*)&krow[32 + lg * 8];
#pragma unroll
        for (int mf = 0; mf < 2; ++mf) {
            f32x4 a = {0.f, 0.f, 0.f, 0.f};
            a = __builtin_amdgcn_mfma_f32_16x16x32_bf16(qa[mf][0], kb0, a, 0, 0, 0);
            a = __builtin_amdgcn_mfma_f32_16x16x32_bf16(qa[mf][1], kb1, a, 0, 0, 0);
#pragma unroll
            for (int r = 0; r < 4; ++r)
                S[mf * 16 + lg * 4 + r][node] = a[r] * 0.125f;
        }
    }
    __syncthreads();

    // phase 2: masked softmax, wave w owns rows [w*8, w*8+8)
#pragma unroll 1
    for (int qi = w * 8; qi < w * 8 + 8; ++qi) {
        float mx = -3.4e38f;
#pragma unroll
        for (int e = 0; e < 8; ++e) {
            int c = l + 64 * e;
            mx = fmaxf(mx, (c < cnt) ? S[qi][c] : -3.4e38f);
        }
#pragma unroll
        for (int o = 32; o; o >>= 1) mx = fmaxf(mx, __shfl_xor(mx, o));
        float sum = 0.f, ev[8];
#pragma unroll
        for (int e = 0; e < 8; ++e) {
            int c = l + 64 * e;
            float s = (c < cnt) ? expf(S[qi][c] - mx) : 0.0f;
            ev[e] = s; sum += s;
        }
#pragma unroll
        for (int o = 32; o; o >>= 1) sum += __shfl_xor(sum, o);
        float inv_s = sum > 0.f ? 1.0f / sum : 0.0f;
#pragma unroll
        for (int e = 0; e < 8; ++e)
            P[qi][l + 64 * e] = (bf16)(ev[e] * inv_s);
    }
    __syncthreads();

    // phase 3: ctx = P @ V ; wave w owns head-dim cols [w*16, w*16+16)
#pragma unroll
    for (int mf = 0; mf < 2; ++mf) {
        f32x4 a = {0.f, 0.f, 0.f, 0.f};
        for (int kc = 0; kc < 16; ++kc) {
            bf16x8 pa = *(const bf16x8*)&P[mf * 16 + lr][kc * 32 + lg * 8];
            bf16x8 vb = *(const bf16x8*)&vt[((size_t)b * 512 + h * HDIM + w * 16 + lr) * 512 + kc * 32 + lg * 8];
            a = __builtin_amdgcn_mfma_f32_16x16x32_bf16(pa, vb, a, 0, 0, 0);
        }
#pragma unroll
        for (int r = 0; r < 4; ++r)
            ctx[(size_t)(b * NQ + mf * 16 + lg * 4 + r) * DIM + h * HDIM + w * 16 + lr] = (bf16)a[r];
    }
}

// ---------------- layernorm (one wave per row) ----------------
// MODE 0: out = LN(x + resid) -> f32 + bf16.  MODE 1: out = gelu(LN(x)) -> bf16 only.

template<int MODE>
__global__ __launch_bounds__(256)
void k_ln(const float* __restrict__ x, const float* __restrict__ resid,
          const float* __restrict__ g, const float* __restrict__ bt,
          float* __restrict__ of, bf16* __restrict__ ob, int D)
{
    int wid = blockIdx.x * 4 + (threadIdx.x >> 6);
    int l = threadIdx.x & 63;
    const int ne = D >> 6;     // 8 (D=512) or 12 (D=768)
    const float* xr = x + (size_t)wid * D;
    float v[12];
    float s = 0.f;
    for (int e = 0; e < ne; ++e) {
        float t = xr[l + 64 * e];
        if (MODE == 0) t += resid[(size_t)wid * D + l + 64 * e];
        v[e] = t; s += t;
    }
#pragma unroll
    for (int o = 32; o; o >>= 1) s += __shfl_xor(s, o);
    float mu = s / D;
    float s2 = 0.f;
    for (int e = 0; e < ne; ++e) { float d = v[e] - mu; s2 += d * d; }
#pragma unroll
    for (int o = 32; o; o >>= 1) s2 += __shfl_xor(s2, o);
    float rst = rsqrtf(s2 / D + 1e-5f);
    for (int e = 0; e < ne; ++e) {
        int c = l + 64 * e;
        float y = (v[e] - mu) * rst * g[c] + bt[c];
        if (MODE == 1) y = gelu_f(y);
        if (MODE == 0) of[(size_t)wid * D + c] = y;
        ob[(size_t)wid * D + c] = (bf16)y;
    }
}

// ---------------- host launch ----------------

extern "C" void kernel_launch(void* const* d_in, const int* in_sizes, int n_in,
                              void* d_out, int out_size, void* d_ws, size_t ws_size,
                              hipStream_t stream)
{
    const float* node = (const float*)d_in[0];
    const float* qt   = (const float*)d_in[1];
    const float* ipw  = (const float*)d_in[2];
    const float* ipb  = (const float*)d_in[3];
    const float* opw  = (const float*)d_in[4];
    const float* opb  = (const float*)d_in[5];
    const float* f1w  = (const float*)d_in[6];
    const float* f1b  = (const float*)d_in[7];
    const float* f2w  = (const float*)d_in[8];
    const float* f2b  = (const float*)d_in[9];
    const float* ln1g = (const float*)d_in[10];
    const float* ln1b = (const float*)d_in[11];
    const float* ln2g = (const float*)d_in[12];
    const float* ln2b = (const float*)d_in[13];
    const float* ow1  = (const float*)d_in[14];
    const float* ob1  = (const float*)d_in[15];
    const float* olng = (const float*)d_in[16];
    const float* olnb = (const float*)d_in[17];
    const float* ow2  = (const float*)d_in[18];
    const float* ob2  = (const float*)d_in[19];
    const int*   bidx = (const int*)d_in[20];

    char* ws = (char*)d_ws;
    size_t off = 0;
    auto alloc = [&](size_t bytes) {
        void* p = ws + off;
        off += (bytes + 255) & ~(size_t)255;
        return p;
    };

    int*  counts = (int*)alloc(BATCH * 4);
    int*  starts = (int*)alloc(BATCH * 4);
    int*  pos    = (int*)alloc((size_t)NB * 4);
    int*  inv    = (int*)alloc((size_t)BATCH * NPG * 4);
    bf16* nodeb  = (bf16*)alloc((size_t)NB * DIM * 2);
    bf16* kbuf   = (bf16*)alloc((size_t)NB * DIM * 2);
    bf16* vtb    = (bf16*)alloc((size_t)BATCH * DIM * NPG * 2);
    bf16* wip    = (bf16*)alloc((size_t)NL * 1536 * DIM * 2);
    bf16* wop    = (bf16*)alloc((size_t)NL * DIM * DIM * 2);
    bf16* wf1    = (bf16*)alloc((size_t)NL * 2048 * DIM * 2);
    bf16* wf2    = (bf16*)alloc((size_t)NL * DIM * 2048 * 2);
    bf16* wo1    = (bf16*)alloc((size_t)LMD * DIM * 2);
    bf16* wo2    = (bf16*)alloc((size_t)LMD * LMD * 2);
    float* hf    = (float*)alloc((size_t)ROWS * DIM * 4);
    bf16* hb     = (bf16*)alloc((size_t)ROWS * DIM * 2);
    bf16* qb     = (bf16*)alloc((size_t)ROWS * DIM * 2);
    bf16* ctxb   = (bf16*)alloc((size_t)ROWS * DIM * 2);
    float* tmp   = (float*)alloc((size_t)ROWS * LMD * 4);
    bf16* fmid   = (bf16*)alloc((size_t)ROWS * 2048 * 2);
    bf16* omid   = (bf16*)alloc((size_t)ROWS * LMD * 2);
    (void)ws_size; (void)in_sizes; (void)n_in; (void)out_size;

    k_init_meta<<<512, 256, 0, stream>>>(counts, inv);
    k_count<<<NB / 256, 256, 0, stream>>>(bidx, counts);
    k_scan<<<1, BATCH, 0, stream>>>(counts, starts);
    k_posinv<<<NB / 256, 256, 0, stream>>>(bidx, starts, pos, inv);
    k_f32_to_bf16<<<2048, 256, 0, stream>>>(node, nodeb, (long)NB * DIM / 4);
    k_f32_to_bf16<<<256, 256, 0, stream>>>(ipw, wip, (long)NL * 1536 * DIM / 4);
    k_f32_to_bf16<<<256, 256, 0, stream>>>(opw, wop, (long)NL * DIM * DIM / 4);
    k_f32_to_bf16<<<256, 256, 0, stream>>>(f1w, wf1, (long)NL * 2048 * DIM / 4);
    k_f32_to_bf16<<<256, 256, 0, stream>>>(f2w, wf2, (long)NL * DIM * 2048 / 4);
    k_f32_to_bf16<<<256, 256, 0, stream>>>(ow1, wo1, (long)LMD * DIM / 4);
    k_f32_to_bf16<<<256, 256, 0, stream>>>(ow2, wo2, (long)LMD * LMD / 4);
    k_init_h<<<2048, 256, 0, stream>>>(qt, hf, hb);

    for (int lyr = 0; lyr < NL; ++lyr) {
        const bf16* wq  = wip + (size_t)lyr * 1536 * DIM;
        const bf16* wkv = wq + (size_t)512 * DIM;
        const float* bq  = ipb + lyr * 1536;
        const float* bkv = bq + 512;

        dim3 gkv(1024 / 128, NB / 128);
        k_gemm_bt<EPI_KV><<<gkv, 256, 0, stream>>>(nodeb, wkv, bkv, kbuf, DIM, 1024, vtb, bidx, pos);

        dim3 gq(DIM / 128, ROWS / 128);
        k_gemm_bt<EPI_BF16><<<gq, 256, 0, stream>>>(hb, wq, bq, qb, DIM, DIM, nullptr, nullptr, nullptr);

        k_attn<<<BATCH * NH, 256, 0, stream>>>(qb, kbuf, vtb, inv, counts, ctxb);

        k_gemm_bt<EPI_F32><<<gq, 256, 0, stream>>>(ctxb, wop + (size_t)lyr * DIM * DIM,
                                                   opb + lyr * DIM, tmp, DIM, DIM,
                                                   nullptr, nullptr, nullptr);
        k_ln<0><<<ROWS / 4, 256, 0, stream>>>(tmp, hf, ln1g + lyr * DIM, ln1b + lyr * DIM, hf, hb, DIM);

        dim3 gf1(2048 / 128, ROWS / 128);
        k_gemm_bt<EPI_BF16_GELU><<<gf1, 256, 0, stream>>>(hb, wf1 + (size_t)lyr * 2048 * DIM,
                                                          f1b + lyr * 2048, fmid, DIM, 2048,
                                                          nullptr, nullptr, nullptr);
        k_gemm_bt<EPI_F32><<<gq, 256, 0, stream>>>(fmid, wf2 + (size_t)lyr * DIM * 2048,
                                                   f2b + lyr * DIM, tmp, 2048, DIM,
                                                   nullptr, nullptr, nullptr);
        k_ln<0><<<ROWS / 4, 256, 0, stream>>>(tmp, hf, ln2g + lyr * DIM, ln2b + lyr * DIM, hf, hb, DIM);
    }

    dim3 go1(LMD / 128, ROWS / 128);
    k_gemm_bt<EPI_F32><<<go1, 256, 0, stream>>>(hb, wo1, ob1, tmp, DIM, LMD, nullptr, nullptr, nullptr);
    k_ln<1><<<ROWS / 4, 256, 0, stream>>>(tmp, nullptr, olng, olnb, nullptr, omid, LMD);
    k_gemm_bt<EPI_F32><<<go1, 256, 0, stream>>>(omid, wo2, ob2, (float*)d_out, LMD, LMD, nullptr, nullptr, nullptr);
}